// Round 8
// baseline (230.507 us; speedup 1.0000x reference)
//
#include <hip/hip_runtime.h>
#include <hip/hip_bf16.h>
#include <cstdint>

#define BATCH 16
#define ATTRS 84
#define NC    80
#define HH    160
#define WW    160
#define HWSZ  (HH * WW)      // 25600
#define KTOP  100
#define CAP   8192
#define XGATE 2.9444389791664403f   // logit(0.95): sigmoid(x)>=0.95 <=> x>=XGATE
#define LDW   48             // LDS row stride (floats), quarter tile + 4+4 halo
#define LCAP  64             // per-WG candidate buffer (expected ~1.6/WG)
#define CSTR  16             // counts stride (u32) -> one cacheline per counter

__device__ __forceinline__ float sigf(float x) {
    return 1.0f / (1.0f + __expf(-x));
}

// ---------------------------------------------------------------------------
// Kernel 1: per-(b,h,quarter) WG, 320 threads. Gate-first NMS:
//   A: coalesced raw copy -> LDS sg[80][48] (w = w0-4+j), 1 barrier
//   B: per-thread gate test of 10 centers from registers (no hmax pass)
//   C': rare gated centers (~0.16%) read their 5x5 raw window from LDS
// 2 barriers total, ~16 KB LDS -> 6 WGs/CU (30 waves, vs 25 in round 6).
// ---------------------------------------------------------------------------
__global__ __launch_bounds__(320, 8) void k_nms(const float* __restrict__ in,
                                                unsigned long long* __restrict__ gather,
                                                unsigned int* __restrict__ counts) {
    const int wg  = blockIdx.x;           // b*(HH*4) + h*4 + q
    const int b   = wg / (HH * 4);
    const int rem = wg % (HH * 4);
    const int h   = rem >> 2;
    const int q   = rem & 3;
    const int t   = (int)threadIdx.x;

    __shared__ float sg[NC][LDW];
    __shared__ unsigned long long lbuf[LCAP];
    __shared__ unsigned int lcount;
    __shared__ unsigned int gbase;

    if (t == 0) lcount = 0;

    const int w0 = q * 40;                // first center column
    // LDS j=0 corresponds to w = w0 - 4
    const float* slab = in + ((size_t)b * ATTRS + 4) * HWSZ + (size_t)h * WW + (w0 - 4);

    // ---- Phase A: coalesced raw copy -> LDS (12 float4 per class row) ----
    // f4 id: c = f4/12, j4 = f4%12 -> w span [w0-4+4*j4, w0+4*j4). The only
    // fully-OOB quads are (q==0,j4==0) and (q==3,j4==11); no partial quads.
#pragma unroll
    for (int it = 0; it < 3; ++it) {
        const int f4 = it * 320 + t;      // 0..959
        const int c  = f4 / 12;
        const int j4 = f4 % 12;
        const bool oob = (q == 0 && j4 == 0) || (q == 3 && j4 == 11);
        float4 v;
        if (oob) {
            v.x = -INFINITY; v.y = -INFINITY; v.z = -INFINITY; v.w = -INFINITY;
        } else {
            v = *reinterpret_cast<const float4*>(slab + (size_t)c * HWSZ + j4 * 4);
        }
        *reinterpret_cast<float4*>(&sg[c][j4 * 4]) = v;
    }
    __syncthreads();

    // ---- Phase B: register gate test of 10 centers ----
    const int c    = t % NC;              // class row 0..79
    const int wq2  = t / NC;              // 0..3, 10 centers each
    const int cj0  = 4 + wq2 * 10;        // j of first center

    float s_[14];                          // raw values at j = cj0-2 .. cj0+11
#pragma unroll
    for (int k = 0; k < 7; ++k) {
        const float2 v2 = *reinterpret_cast<const float2*>(&sg[c][cj0 - 2 + 2 * k]);
        s_[2 * k + 0] = v2.x;
        s_[2 * k + 1] = v2.y;
    }

    const int r0 = max(c - 2, 0), r1 = max(c - 1, 0);
    const int r3 = min(c + 1, NC - 1), r4 = min(c + 2, NC - 1);

#pragma unroll
    for (int i = 0; i < 10; ++i) {
        const float x = s_[i + 2];        // center value, j = cj0 + i
        if (x >= XGATE) {                 // rare (~0.16%): full 5x5 window test
            const int j = cj0 + i;
            float vm = -INFINITY;
#pragma unroll
            for (int dj = -2; dj <= 2; ++dj) {
                const int jj = j + dj;
                vm = fmaxf(vm, sg[r0][jj]);
                vm = fmaxf(vm, sg[r1][jj]);
                vm = fmaxf(vm, sg[c ][jj]);
                vm = fmaxf(vm, sg[r3][jj]);
                vm = fmaxf(vm, sg[r4][jj]);
            }
            if (x == vm) {
                const float ssc = sigf(x);
                const int w = w0 + wq2 * 10 + i;                 // global column
                const unsigned idx = (unsigned)(c * HWSZ + h * WW + w);  // < 2^21
                unsigned long long key =
                    ((unsigned long long)__float_as_uint(ssc) << 21) |
                    (unsigned long long)(0x1FFFFFu - idx);       // score desc, idx asc
                unsigned p = atomicAdd(&lcount, 1u);
                if (p < LCAP) {
                    lbuf[p] = key;
                } else {  // statistically unreachable; exactness fallback
                    unsigned g = atomicAdd(&counts[b * CSTR], 1u);
                    if (g < CAP) gather[(size_t)b * CAP + g] = key;
                }
            }
        }
    }
    __syncthreads();

    // ---- Flush: one global atomic per WG, coalesced bulk copy ----
    const unsigned n = min(lcount, (unsigned)LCAP);
    if (t == 0 && n > 0) gbase = atomicAdd(&counts[b * CSTR], n);
    __syncthreads();
    for (unsigned i = t; i < n; i += 320) {
        unsigned g = gbase + i;
        if (g < CAP) gather[(size_t)b * CAP + g] = lbuf[i];
    }
}

// ---------------------------------------------------------------------------
// Kernel 2: per-batch exact top-100 selection from gathered candidates.
// ---------------------------------------------------------------------------
__global__ __launch_bounds__(256) void k_select(const unsigned long long* __restrict__ gather,
                                                const unsigned int* __restrict__ counts,
                                                unsigned int* __restrict__ picks) {
    const int b = blockIdx.x;
    const int t = (int)threadIdx.x;

    __shared__ unsigned int hist[2048];       // 8 KB
    __shared__ unsigned int chunksum[256];
    __shared__ unsigned long long compact[512];
    __shared__ unsigned int ncompact;
    __shared__ int b2_sh;

    const int M = min(counts[b * CSTR], (unsigned)CAP);
    const unsigned long long* keys = gather + (size_t)b * CAP;

    for (int i = t; i < 2048; i += 256) hist[i] = 0;
    if (t == 0) ncompact = 0;
    __syncthreads();

    for (int i = t; i < M; i += 256) {
        unsigned sb = (unsigned)(keys[i] >> 21);
        int bk = (int)((sb - 0x3F700000u) >> 9);
        bk = min(max(bk, 0), 2047);
        atomicAdd(&hist[bk], 1u);
    }
    __syncthreads();

    unsigned sum = 0;
#pragma unroll
    for (int j = 0; j < 8; ++j) sum += hist[t * 8 + j];
    chunksum[t] = sum;
    __syncthreads();
    for (int off = 1; off < 256; off <<= 1) {
        unsigned v = (t + off < 256) ? chunksum[t + off] : 0u;
        __syncthreads();
        chunksum[t] += v;
        __syncthreads();
    }

    const int target = (M < KTOP) ? M : KTOP;
    if (target > 0 &&
        (int)chunksum[t] >= target && (t == 255 || (int)chunksum[t + 1] < target)) {
        unsigned cum = (t == 255) ? 0u : chunksum[t + 1];
        int bsel = t * 8;
        for (int j = 7; j >= 0; --j) {
            cum += hist[t * 8 + j];
            if ((int)cum >= target) { bsel = t * 8 + j; break; }
        }
        b2_sh = bsel;
    }
    __syncthreads();
    const int b2 = b2_sh;

    for (int i = t; i < M; i += 256) {
        unsigned long long k = keys[i];
        unsigned sb = (unsigned)(k >> 21);
        int bk = min(max((int)((sb - 0x3F700000u) >> 9), 0), 2047);
        if (bk >= b2) {
            unsigned p = atomicAdd(&ncompact, 1u);
            if (p < 512) compact[p] = k;
        }
    }
    __syncthreads();

    const int N = (int)min(ncompact, 512u);
    for (int i = t; i < N; i += 256) {
        unsigned long long ki = compact[i];
        int rank = 0;
        for (int j = 0; j < N; ++j) rank += (compact[j] > ki) ? 1 : 0;
        if (rank < KTOP) {
            unsigned idx = 0x1FFFFFu - (unsigned)(ki & 0x1FFFFFu);
            picks[b * KTOP + rank] = idx % HWSZ;   // spatial index
        }
    }
}

// ---------------------------------------------------------------------------
// Kernel 3: one WG per pick. Box decode + suppressed 80-class row.
// ---------------------------------------------------------------------------
__global__ __launch_bounds__(128) void k_emit(const float* __restrict__ in,
                                              const unsigned int* __restrict__ picks,
                                              float* __restrict__ out) {
    const int pk = blockIdx.x;            // b*KTOP + k
    const int b  = pk / KTOP;
    const int t  = (int)threadIdx.x;
    const unsigned hw = picks[pk];
    const int h = (int)(hw / WW), w = (int)(hw % WW);

    __shared__ float tile[NC][5];

    const float* base = in + (size_t)b * ATTRS * HWSZ;

    if (t < NC) {
        const int c = t;
        // aligned 8-float span covering [w-2, w+2] clamped to the row
        int a0 = (max(w - 2, 0)) & ~3;
        a0 = min(a0, WW - 8);
        const float* rp = base + (size_t)(4 + c) * HWSZ + (size_t)h * WW;
        const float4 f0 = *reinterpret_cast<const float4*>(rp + a0);
        const float4 f1 = *reinterpret_cast<const float4*>(rp + a0 + 4);
        float sp[8] = { f0.x, f0.y, f0.z, f0.w, f1.x, f1.y, f1.z, f1.w };
#pragma unroll
        for (int j = 0; j < 5; ++j) {
            const int wc = w + j - 2;
            float vv = -INFINITY;
            if (wc >= 0 && wc < WW) vv = sigf(sp[wc - a0]);
            tile[c][j] = vv;
        }
    }
    __syncthreads();

    float* orow = out + (size_t)pk * (5 + NC);

    if (t < 4) {
        float v = base[(size_t)t * HWSZ + hw];
        float r;
        if (t == 0)      r = (sigf(v) + (float)w) * 8.0f;
        else if (t == 1) r = (sigf(v) + (float)h) * 8.0f;
        else             r = expf(v) * 64.0f;     // exp(.)*SIGAMA*STRIDE
        orow[t] = r;
    }
    if (t == 4) orow[4] = 1.0f;

    if (t < NC) {
        const int c = t;
        const int cl = max(0, c - 2), ch = min(NC - 1, c + 2);
        float m = -INFINITY;
        for (int cc = cl; cc <= ch; ++cc) {
#pragma unroll
            for (int j = 0; j < 5; ++j) m = fmaxf(m, tile[cc][j]);
        }
        float sc = tile[c][2];
        orow[5 + c] = (sc == m) ? sc : 0.0f;
    }
}

// ---------------------------------------------------------------------------
extern "C" void kernel_launch(void* const* d_in, const int* in_sizes, int n_in,
                              void* d_out, int out_size, void* d_ws, size_t ws_size,
                              hipStream_t stream) {
    const float* in = (const float*)d_in[0];
    float* out = (float*)d_out;

    // workspace layout
    unsigned int* counts = (unsigned int*)d_ws;                               // 16 * CSTR u32 (1 KB)
    unsigned int* picks  = (unsigned int*)((char*)d_ws + 1024);               // 1600 u32
    unsigned long long* gather = (unsigned long long*)((char*)d_ws + 8192);   // 16*CAP u64

    hipMemsetAsync(d_ws, 0, 1024, stream);  // zero candidate counters

    k_nms<<<BATCH * HH * 4, 320, 0, stream>>>(in, gather, counts);
    k_select<<<BATCH, 256, 0, stream>>>(gather, counts, picks);
    k_emit<<<BATCH * KTOP, 128, 0, stream>>>(in, picks, out);
}